// Round 2
// baseline (441.622 us; speedup 1.0000x reference)
//
#include <hip/hip_runtime.h>
#include <cstdint>

#define HID 256
static constexpr int    NNODES = 100000;
static constexpr int    NEDGES = 300000;
static constexpr size_t NH     = (size_t)NNODES * HID;  // 25,600,000 elems
static constexpr int    SCAN_B = 256;
static constexpr int    NSBLK  = (NNODES + SCAN_B - 1) / SCAN_B;  // 391

typedef __attribute__((ext_vector_type(8))) short bf16x8;
typedef __attribute__((ext_vector_type(4))) float f32x4;

__device__ __forceinline__ unsigned short f2bf(float x) {   // RNE f32 -> bf16
    unsigned int u = __float_as_uint(x);
    u += 0x7fffu + ((u >> 16) & 1u);
    return (unsigned short)(u >> 16);
}
__device__ __forceinline__ unsigned int pack2(float a, float b) {
    return (unsigned int)f2bf(a) | ((unsigned int)f2bf(b) << 16);
}
__device__ __forceinline__ float bflo(unsigned int u) { return __uint_as_float(u << 16); }
__device__ __forceinline__ float bfhi(unsigned int u) { return __uint_as_float(u & 0xffff0000u); }

// ---------------------------------------------------------------- zero ints
__global__ void zero_i32_k(int* __restrict__ p, int n) {
    int i = blockIdx.x * blockDim.x + threadIdx.x;
    if (i < n) p[i] = 0;
}

// ---------------------------------------------------------------- degrees
__global__ void count_deg_k(const int* __restrict__ src, const int* __restrict__ dst,
                            int* __restrict__ degout, int* __restrict__ degin) {
    int e = blockIdx.x * blockDim.x + threadIdx.x;
    if (e < NEDGES) {
        atomicAdd(degout + src[e], 1);
        atomicAdd(degin  + dst[e], 1);
    }
}

// ---------------------------------------------------------------- weights -> bf16 (one launch)
// blocks 0..127: fc_w0, 128..191: fc_w1, 192..223: fc_w2, 224..479: gc2_w transpose
__global__ void cvt_weights_k(const float* __restrict__ w0, const float* __restrict__ w1,
                              const float* __restrict__ w2, const float* __restrict__ wg,
                              unsigned short* __restrict__ o0, unsigned short* __restrict__ o1,
                              unsigned short* __restrict__ o2, unsigned short* __restrict__ ogT) {
    int b = blockIdx.x, t = threadIdx.x;
    const float* in; unsigned short* out; int i;
    if (b < 128)      { in = w0; out = o0; i = b * 256 + t; }
    else if (b < 192) { in = w1; out = o1; i = (b - 128) * 256 + t; }
    else if (b < 224) { in = w2; out = o2; i = (b - 192) * 256 + t; }
    else {
        int n = b - 224, k = t;
        ogT[n * 256 + k] = f2bf(wg[k * 256 + n]);
        return;
    }
    float4 v = ((const float4*)in)[i];
    ushort4 w;
    w.x = f2bf(v.x); w.y = f2bf(v.y); w.z = f2bf(v.z); w.w = f2bf(v.w);
    ((ushort4*)out)[i] = w;
}

// ---------------------------------------------------------------- scan A (+ norms fused)
__global__ void scan_a_k(const int* __restrict__ degin, const int* __restrict__ degout,
                         int* __restrict__ row_off, int* __restrict__ bsums,
                         float* __restrict__ nout, float* __restrict__ nin,
                         const float* __restrict__ sw, float* __restrict__ tail) {
    __shared__ int sm[SCAN_B];
    int t = threadIdx.x;
    int g = blockIdx.x * SCAN_B + t;
    int v = (g < NNODES) ? degin[g] : 0;
    sm[t] = v;
    if (g < NNODES) {
        nout[g] = rsqrtf(fmaxf((float)degout[g], 1.0f));
        nin[g]  = rsqrtf(fmaxf((float)v, 1.0f));
    }
    if (g < 5) tail[g] = sw[g];   // semantic_weight passthrough
    __syncthreads();
#pragma unroll
    for (int off = 1; off < SCAN_B; off <<= 1) {
        int x = (t >= off) ? sm[t - off] : 0;
        __syncthreads();
        sm[t] += x;
        __syncthreads();
    }
    if (g < NNODES) row_off[g] = sm[t] - v;
    if (t == SCAN_B - 1) bsums[blockIdx.x] = sm[t];
}

__global__ void scan_b_k(int* __restrict__ bsums) {
    __shared__ int sm[512];
    int t = threadIdx.x;
    int v = (t < NSBLK) ? bsums[t] : 0;
    sm[t] = v;
    __syncthreads();
#pragma unroll
    for (int off = 1; off < 512; off <<= 1) {
        int x = (t >= off) ? sm[t - off] : 0;
        __syncthreads();
        sm[t] += x;
        __syncthreads();
    }
    if (t < NSBLK) bsums[t] = sm[t] - v;
}

__global__ void scan_c_k(int* __restrict__ row_off, const int* __restrict__ bsums) {
    int g = blockIdx.x * SCAN_B + threadIdx.x;
    if (g < NNODES) row_off[g] += bsums[blockIdx.x];
    if (g == 0) row_off[NNODES] = NEDGES;
}

// ---------------------------------------------------------------- CSR fill
__global__ void fill_csr_k(const int* __restrict__ src, const int* __restrict__ dst,
                           const int* __restrict__ row_off, int* __restrict__ cursor,
                           int* __restrict__ csr_src) {
    int e = blockIdx.x * blockDim.x + threadIdx.x;
    if (e < NEDGES) {
        int d = dst[e];
        int pos = row_off[d] + atomicAdd(cursor + d, 1);
        csr_src[pos] = src[e];
    }
}

// ---------------------------------------------------------------- gather (wave per node)
template <int EPI>
__global__ __launch_bounds__(256) void gather_k(
    const unsigned short* __restrict__ h, const int* __restrict__ row_off,
    const int* __restrict__ csr_src, const float* __restrict__ nin,
    const float* __restrict__ bias, void* __restrict__ outv)
{
    int node = blockIdx.x * 4 + (threadIdx.x >> 6);
    if (node >= NNODES) return;
    int lane = threadIdx.x & 63;
    int beg = row_off[node], end = row_off[node + 1];
    float a0 = 0.f, a1 = 0.f, a2 = 0.f, a3 = 0.f;
    for (int base = beg; base < end; base += 64) {
        int cnt = end - base; if (cnt > 64) cnt = 64;
        int idx = csr_src[base + (lane < cnt ? lane : cnt - 1)];   // coalesced
        int j = 0;
        for (; j + 4 <= cnt; j += 4) {
            int s0 = __shfl(idx, j);
            int s1 = __shfl(idx, j + 1);
            int s2 = __shfl(idx, j + 2);
            int s3 = __shfl(idx, j + 3);
            uint2 v0 = *(const uint2*)(h + (size_t)s0 * HID + lane * 4);
            uint2 v1 = *(const uint2*)(h + (size_t)s1 * HID + lane * 4);
            uint2 v2 = *(const uint2*)(h + (size_t)s2 * HID + lane * 4);
            uint2 v3 = *(const uint2*)(h + (size_t)s3 * HID + lane * 4);
            a0 += bflo(v0.x) + bflo(v1.x) + bflo(v2.x) + bflo(v3.x);
            a1 += bfhi(v0.x) + bfhi(v1.x) + bfhi(v2.x) + bfhi(v3.x);
            a2 += bflo(v0.y) + bflo(v1.y) + bflo(v2.y) + bflo(v3.y);
            a3 += bfhi(v0.y) + bfhi(v1.y) + bfhi(v2.y) + bfhi(v3.y);
        }
        for (; j < cnt; ++j) {
            int s = __shfl(idx, j);
            uint2 v = *(const uint2*)(h + (size_t)s * HID + lane * 4);
            a0 += bflo(v.x); a1 += bfhi(v.x);
            a2 += bflo(v.y); a3 += bfhi(v.y);
        }
    }
    if (EPI) {
        float ni = nin[node];
        float4 bb = *(const float4*)(bias + lane * 4);
        float4 o;
        o.x = fmaxf(fmaf(a0, ni, bb.x), 0.f);
        o.y = fmaxf(fmaf(a1, ni, bb.y), 0.f);
        o.z = fmaxf(fmaf(a2, ni, bb.z), 0.f);
        o.w = fmaxf(fmaf(a3, ni, bb.w), 0.f);
        *(float4*)((float*)outv + (size_t)node * HID + lane * 4) = o;
    } else {
        ushort4 o;
        o.x = f2bf(a0); o.y = f2bf(a1); o.z = f2bf(a2); o.w = f2bf(a3);
        *(ushort4*)((unsigned short*)outv + (size_t)node * HID + lane * 4) = o;
    }
}

// ---------------------------------------------------------------- projection MFMA GEMM (v3)
// Tile 128m x 256n, 8 waves (2m x 4n), 512 threads, BK=32.
//   - A: fp32 -> reg prefetch DEPTH 2 (E/O pairs) -> bf16 pack -> dbuf LDS (2x8KB)
//   - B: per-wave fragments direct from global (L2-resident), issued pre-barrier,
//     n-REMAPPED: fragment slot (j,l15) holds neuron wn*64 + l15*4 + j, so each
//     lane's 4 j-accumulators are 4 consecutive output columns (ushort4 stores).
//   - one s_barrier + lgkmcnt(0) per k-step; no vmcnt drain at barriers.
__global__ __launch_bounds__(512, 4) void proj_mfma_k(
    const float* __restrict__ f0, const float* __restrict__ f1, const float* __restrict__ f2,
    const unsigned short* __restrict__ w0, const unsigned short* __restrict__ w1,
    const unsigned short* __restrict__ w2,
    const float* __restrict__ b0, const float* __restrict__ b1, const float* __restrict__ b2,
    const float* __restrict__ nout, unsigned short* __restrict__ h0)
{
    __shared__ unsigned short As[2][128 * 32];   // 2 x 8 KB

    int bx = blockIdx.x;
    const float* A; const unsigned short* B; const float* bias; const float* rs;
    unsigned short* C; int M, K;
    if (bx < 313)       { A = f0; B = w0; bias = b0; rs = nout;          C = h0;                          M = 40000; K = 512; }
    else if (bx < 548)  { bx -= 313; A = f1; B = w1; bias = b1; rs = nout + 40000; C = h0 + (size_t)40000 * HID; M = 30000; K = 256; }
    else                { bx -= 548; A = f2; B = w2; bias = b2; rs = nout + 70000; C = h0 + (size_t)70000 * HID; M = 30000; K = 128; }
    const int m0 = bx * 128;

    const int tid  = threadIdx.x;
    const int wid  = tid >> 6;
    const int wm   = wid >> 2;       // 0..1  (m-wave)
    const int wn   = wid & 3;        // 0..3  (n-wave)
    const int lane = tid & 63;
    const int half = lane >> 4;
    const int l15  = lane & 15;

    f32x4 acc[4][4];
#pragma unroll
    for (int i = 0; i < 4; ++i)
#pragma unroll
        for (int j = 0; j < 4; ++j)
#pragma unroll
            for (int r = 0; r < 4; ++r) acc[i][j][r] = 0.f;

    const int arow = tid >> 2, ac = tid & 3;     // arow 0..127
    const int aslot = ac ^ ((arow >> 1) & 3);
    int agm = m0 + arow; if (agm > M - 1) agm = M - 1;
    const float* ap = A + (size_t)agm * K + ac * 8;

    // n-remap: fragment slot (j,l15) <- weight row wn*64 + l15*4 + j
    const unsigned short* bp = B + (size_t)(wn * 64 + l15 * 4) * K + half * 8;

    const int nT = K >> 5;   // 16 / 8 / 4 (always even)

    // ---- prologue: A prefetch depth 2 ----
    float4 a0E = *(const float4*)ap;
    float4 a1E = *(const float4*)(ap + 4);
    float4 a0O = *(const float4*)(ap + 32);
    float4 a1O = *(const float4*)(ap + 36);
    bf16x8 bcur[4];

#define PROJ_STEP(P, A0, A1)                                                   \
    {                                                                          \
        uint4 u;                                                               \
        u.x = pack2(A0.x, A0.y); u.y = pack2(A0.z, A0.w);                      \
        u.z = pack2(A1.x, A1.y); u.w = pack2(A1.z, A1.w);                      \
        *(uint4*)&As[P][(arow * 4 + aslot) * 8] = u;                           \
        _Pragma("unroll")                                                      \
        for (int j = 0; j < 4; ++j)                                            \
            bcur[j] = *(const bf16x8*)(bp + (size_t)j * K + (tt + P) * 32);    \
        asm volatile("s_waitcnt lgkmcnt(0)" ::: "memory");                     \
        __builtin_amdgcn_s_barrier();                                          \
        __builtin_amdgcn_sched_barrier(0);                                     \
        {                                                                      \
            int tf = tt + P + 2; if (tf > nT - 1) tf = nT - 1;                 \
            const float* pn = ap + tf * 32;                                    \
            A0 = *(const float4*)pn; A1 = *(const float4*)(pn + 4);            \
        }                                                                      \
        bf16x8 af[4];                                                          \
        _Pragma("unroll")                                                      \
        for (int i = 0; i < 4; ++i) {                                          \
            int m = wm * 64 + i * 16 + l15;                                    \
            int ca = half ^ ((m >> 1) & 3);                                    \
            af[i] = *(const bf16x8*)&As[P][(m * 4 + ca) * 8];                  \
        }                                                                      \
        _Pragma("unroll")                                                      \
        for (int i = 0; i < 4; ++i)                                            \
            _Pragma("unroll")                                                  \
            for (int j = 0; j < 4; ++j)                                        \
                acc[i][j] = __builtin_amdgcn_mfma_f32_16x16x32_bf16(           \
                    af[i], bcur[j], acc[i][j], 0, 0, 0);                       \
    }

    for (int tt = 0; tt < nT; tt += 2) {
        PROJ_STEP(0, a0E, a1E)
        PROJ_STEP(1, a0O, a1O)
    }
#undef PROJ_STEP

    // ---- epilogue: lane's 4 j-values are consecutive cols -> ushort4 stores
    float4 bb = *(const float4*)(bias + wn * 64 + l15 * 4);
    const int mwb = m0 + wm * 64;
#pragma unroll
    for (int i = 0; i < 4; ++i) {
        int mb = mwb + i * 16 + half * 4;
        if (mb >= M) continue;                 // M % 4 == 0: quad all-valid
        float4 rv = *(const float4*)(rs + mb);
#pragma unroll
        for (int r = 0; r < 4; ++r) {
            float rsm = (&rv.x)[r];
            ushort4 o;
            o.x = f2bf((acc[i][0][r] + bb.x) * rsm);
            o.y = f2bf((acc[i][1][r] + bb.y) * rsm);
            o.z = f2bf((acc[i][2][r] + bb.z) * rsm);
            o.w = f2bf((acc[i][3][r] + bb.w) * rsm);
            *(ushort4*)&C[(size_t)(mb + r) * HID + wn * 64 + l15 * 4] = o;
        }
    }
}

// ---------------------------------------------------------------- mid GEMM (v3, same structure)
// h2pre[m][n] = sum_k epi(agg1[m][k]) * W[k][n],
//   epi(x) = relu(x * nin[m] + b1[k]) * nout[m]   (layer-1 epilogue in staging)
__global__ __launch_bounds__(512, 4) void mid_mfma_k(
    const unsigned short* __restrict__ agg1, const unsigned short* __restrict__ wT,
    const float* __restrict__ b1, const float* __restrict__ nin,
    const float* __restrict__ nout, unsigned short* __restrict__ h2)
{
    __shared__ unsigned short As[2][128 * 32];   // 2 x 8 KB

    const int m0   = blockIdx.x * 128;
    const int tid  = threadIdx.x;
    const int wid  = tid >> 6;
    const int wm   = wid >> 2;
    const int wn   = wid & 3;
    const int lane = tid & 63;
    const int half = lane >> 4;
    const int l15  = lane & 15;

    f32x4 acc[4][4];
#pragma unroll
    for (int i = 0; i < 4; ++i)
#pragma unroll
        for (int j = 0; j < 4; ++j)
#pragma unroll
            for (int r = 0; r < 4; ++r) acc[i][j][r] = 0.f;

    const int arow = tid >> 2, ac = tid & 3;
    const int aslot = ac ^ ((arow >> 1) & 3);
    int agm = m0 + arow; if (agm > NNODES - 1) agm = NNODES - 1;
    const float ni = nin[agm], no = nout[agm];
    const unsigned short* ap = agg1 + (size_t)agm * HID + ac * 8;
    const unsigned short* bp = wT + (size_t)(wn * 64 + l15 * 4) * 256 + half * 8;

    // ---- prologue: depth-2 prefetch of A chunks and bias chunks ----
    uint4  auE = *(const uint4*)ap;
    uint4  auO = *(const uint4*)(ap + 32);
    float4 cE0 = *(const float4*)(b1 + ac * 8);
    float4 cE1 = *(const float4*)(b1 + ac * 8 + 4);
    float4 cO0 = *(const float4*)(b1 + 32 + ac * 8);
    float4 cO1 = *(const float4*)(b1 + 32 + ac * 8 + 4);
    bf16x8 bcur[4];

#define MID_STEP(P, AU, C0, C1)                                                \
    {                                                                          \
        float x0 = fmaxf(fmaf(bflo(AU.x), ni, C0.x), 0.f) * no;                \
        float x1 = fmaxf(fmaf(bfhi(AU.x), ni, C0.y), 0.f) * no;                \
        float x2 = fmaxf(fmaf(bflo(AU.y), ni, C0.z), 0.f) * no;                \
        float x3 = fmaxf(fmaf(bfhi(AU.y), ni, C0.w), 0.f) * no;                \
        float x4 = fmaxf(fmaf(bflo(AU.z), ni, C1.x), 0.f) * no;                \
        float x5 = fmaxf(fmaf(bfhi(AU.z), ni, C1.y), 0.f) * no;                \
        float x6 = fmaxf(fmaf(bflo(AU.w), ni, C1.z), 0.f) * no;                \
        float x7 = fmaxf(fmaf(bfhi(AU.w), ni, C1.w), 0.f) * no;                \
        uint4 o;                                                               \
        o.x = pack2(x0, x1); o.y = pack2(x2, x3);                              \
        o.z = pack2(x4, x5); o.w = pack2(x6, x7);                              \
        *(uint4*)&As[P][(arow * 4 + aslot) * 8] = o;                           \
        _Pragma("unroll")                                                      \
        for (int j = 0; j < 4; ++j)                                            \
            bcur[j] = *(const bf16x8*)(bp + j * 256 + (tt + P) * 32);          \
        asm volatile("s_waitcnt lgkmcnt(0)" ::: "memory");                     \
        __builtin_amdgcn_s_barrier();                                          \
        __builtin_amdgcn_sched_barrier(0);                                     \
        {                                                                      \
            int tf = tt + P + 2; if (tf > 7) tf = 7;                           \
            AU = *(const uint4*)(ap + tf * 32);                                \
            C0 = *(const float4*)(b1 + tf * 32 + ac * 8);                      \
            C1 = *(const float4*)(b1 + tf * 32 + ac * 8 + 4);                  \
        }                                                                      \
        bf16x8 af[4];                                                          \
        _Pragma("unroll")                                                      \
        for (int i = 0; i < 4; ++i) {                                          \
            int m = wm * 64 + i * 16 + l15;                                    \
            int ca = half ^ ((m >> 1) & 3);                                    \
            af[i] = *(const bf16x8*)&As[P][(m * 4 + ca) * 8];                  \
        }                                                                      \
        _Pragma("unroll")                                                      \
        for (int i = 0; i < 4; ++i)                                            \
            _Pragma("unroll")                                                  \
            for (int j = 0; j < 4; ++j)                                        \
                acc[i][j] = __builtin_amdgcn_mfma_f32_16x16x32_bf16(           \
                    af[i], bcur[j], acc[i][j], 0, 0, 0);                       \
    }

    for (int tt = 0; tt < 8; tt += 2) {
        MID_STEP(0, auE, cE0, cE1)
        MID_STEP(1, auO, cO0, cO1)
    }
#undef MID_STEP

    const int mwb = m0 + wm * 64;
#pragma unroll
    for (int i = 0; i < 4; ++i) {
        int mb = mwb + i * 16 + half * 4;
        if (mb >= NNODES) continue;            // NNODES % 4 == 0
#pragma unroll
        for (int r = 0; r < 4; ++r) {
            ushort4 o;
            o.x = f2bf(acc[i][0][r]);
            o.y = f2bf(acc[i][1][r]);
            o.z = f2bf(acc[i][2][r]);
            o.w = f2bf(acc[i][3][r]);
            *(ushort4*)&h2[(size_t)(mb + r) * HID + wn * 64 + l15 * 4] = o;
        }
    }
}

// ---------------------------------------------------------------- launch
extern "C" void kernel_launch(void* const* d_in, const int* in_sizes, int n_in,
                              void* d_out, int out_size, void* d_ws, size_t ws_size,
                              hipStream_t stream)
{
    const float* feat0    = (const float*)d_in[0];
    const float* feat1    = (const float*)d_in[1];
    const float* feat2    = (const float*)d_in[2];
    const float* fc_w0    = (const float*)d_in[3];
    const float* fc_b0    = (const float*)d_in[4];
    const float* fc_w1    = (const float*)d_in[5];
    const float* fc_b1    = (const float*)d_in[6];
    const float* fc_w2    = (const float*)d_in[7];
    const float* fc_b2    = (const float*)d_in[8];
    const float* gc1_bias = (const float*)d_in[9];
    const float* gc2_w    = (const float*)d_in[10];
    const float* gc2_bias = (const float*)d_in[11];
    const float* sw       = (const float*)d_in[12];
    const int*   src      = (const int*)d_in[13];
    const int*   dst      = (const int*)d_in[14];

    // ---- workspace layout ----
    unsigned short* h0b  = (unsigned short*)d_ws;          // NH bf16 (later h2pre)
    unsigned short* agg1 = h0b + NH;                       // NH bf16
    unsigned short* h2b  = h0b;    // alias: h0 dead after gather1
    unsigned short* w0b  = agg1 + NH;                      // 256*512
    unsigned short* w1b  = w0b + 131072;                   // 256*256
    unsigned short* w2b  = w1b + 65536;                    // 256*128
    unsigned short* w2Tb = w2b + 32768;                    // 256*256 (n-major)
    float* nout = (float*)(w2Tb + 65536);
    float* nin  = nout + NNODES;
    int* deg_out = (int*)(nin + NNODES);
    int* deg_in  = deg_out + NNODES;
    int* cursor  = deg_in + NNODES;
    int* row_off = cursor + NNODES;       // NNODES+1
    int* bsums   = row_off + NNODES + 1;  // 512
    int* csr_src = bsums + 512;           // NEDGES
    float* out   = (float*)d_out;

    // ---- graph preprocessing + weight conversion ----
    zero_i32_k<<<(3 * NNODES + 255) / 256, 256, 0, stream>>>(deg_out, 3 * NNODES);
    cvt_weights_k<<<480, 256, 0, stream>>>(fc_w0, fc_w1, fc_w2, gc2_w,
                                           w0b, w1b, w2b, w2Tb);
    count_deg_k<<<(NEDGES + 255) / 256, 256, 0, stream>>>(src, dst, deg_out, deg_in);
    scan_a_k<<<NSBLK, SCAN_B, 0, stream>>>(deg_in, deg_out, row_off, bsums,
                                           nout, nin, sw, out + NH);
    scan_b_k<<<1, 512, 0, stream>>>(bsums);
    scan_c_k<<<NSBLK, SCAN_B, 0, stream>>>(row_off, bsums);
    fill_csr_k<<<(NEDGES + 255) / 256, 256, 0, stream>>>(src, dst, row_off, cursor, csr_src);

    // ---- projections: h0 = (feat @ W.T + b)*nout  [bf16] ----
    proj_mfma_k<<<783, 512, 0, stream>>>(feat0, feat1, feat2, w0b, w1b, w2b,
                                         fc_b0, fc_b1, fc_b2, nout, h0b);

    // ---- layer 1 aggregate (raw sum): agg1 = A h0 ----
    gather_k<0><<<(NNODES + 3) / 4, 256, 0, stream>>>(h0b, row_off, csr_src,
                                                      nullptr, nullptr, agg1);

    // ---- h2pre = relu(agg1*nin + b1)*nout @ W   (epilogue fused into A-staging) ----
    mid_mfma_k<<<782, 512, 0, stream>>>(agg1, w2Tb, gc1_bias, nin, nout, h2b);

    // ---- layer 2 aggregate + final epilogue -> d_out (fp32) ----
    gather_k<1><<<(NNODES + 3) / 4, 256, 0, stream>>>(h2b, row_off, csr_src,
                                                      nin, gc2_bias, out);
}

// Round 3
// 396.874 us; speedup vs baseline: 1.1128x; 1.1128x over previous
//
#include <hip/hip_runtime.h>
#include <cstdint>

#define HID 256
static constexpr int    NNODES = 100000;
static constexpr int    NEDGES = 300000;
static constexpr size_t NH     = (size_t)NNODES * HID;  // 25,600,000 elems
static constexpr int    SCAN_B = 256;
static constexpr int    NSBLK  = (NNODES + SCAN_B - 1) / SCAN_B;  // 391

typedef __attribute__((ext_vector_type(8))) short bf16x8;
typedef __attribute__((ext_vector_type(4))) float f32x4;

__device__ __forceinline__ unsigned short f2bf(float x) {   // RNE f32 -> bf16
    unsigned int u = __float_as_uint(x);
    u += 0x7fffu + ((u >> 16) & 1u);
    return (unsigned short)(u >> 16);
}
__device__ __forceinline__ unsigned int pack2(float a, float b) {
    return (unsigned int)f2bf(a) | ((unsigned int)f2bf(b) << 16);
}
__device__ __forceinline__ float bflo(unsigned int u) { return __uint_as_float(u << 16); }
__device__ __forceinline__ float bfhi(unsigned int u) { return __uint_as_float(u & 0xffff0000u); }

// ---------------------------------------------------------------- zero ints
__global__ void zero_i32_k(int* __restrict__ p, int n) {
    int i = blockIdx.x * blockDim.x + threadIdx.x;
    if (i < n) p[i] = 0;
}

// ---------------------------------------------------------------- degrees
__global__ void count_deg_k(const int* __restrict__ src, const int* __restrict__ dst,
                            int* __restrict__ degout, int* __restrict__ degin) {
    int e = blockIdx.x * blockDim.x + threadIdx.x;
    if (e < NEDGES) {
        atomicAdd(degout + src[e], 1);
        atomicAdd(degin  + dst[e], 1);
    }
}

// ---------------------------------------------------------------- weights -> bf16 (one launch)
// blocks 0..127: fc_w0, 128..191: fc_w1, 192..223: fc_w2, 224..479: gc2_w transpose
__global__ void cvt_weights_k(const float* __restrict__ w0, const float* __restrict__ w1,
                              const float* __restrict__ w2, const float* __restrict__ wg,
                              unsigned short* __restrict__ o0, unsigned short* __restrict__ o1,
                              unsigned short* __restrict__ o2, unsigned short* __restrict__ ogT) {
    int b = blockIdx.x, t = threadIdx.x;
    const float* in; unsigned short* out; int i;
    if (b < 128)      { in = w0; out = o0; i = b * 256 + t; }
    else if (b < 192) { in = w1; out = o1; i = (b - 128) * 256 + t; }
    else if (b < 224) { in = w2; out = o2; i = (b - 192) * 256 + t; }
    else {
        int n = b - 224, k = t;
        ogT[n * 256 + k] = f2bf(wg[k * 256 + n]);
        return;
    }
    float4 v = ((const float4*)in)[i];
    ushort4 w;
    w.x = f2bf(v.x); w.y = f2bf(v.y); w.z = f2bf(v.z); w.w = f2bf(v.w);
    ((ushort4*)out)[i] = w;
}

// ---------------------------------------------------------------- scan A (+ norms fused)
__global__ void scan_a_k(const int* __restrict__ degin, const int* __restrict__ degout,
                         int* __restrict__ row_off, int* __restrict__ bsums,
                         float* __restrict__ nout, float* __restrict__ nin,
                         const float* __restrict__ sw, float* __restrict__ tail) {
    __shared__ int sm[SCAN_B];
    int t = threadIdx.x;
    int g = blockIdx.x * SCAN_B + t;
    int v = (g < NNODES) ? degin[g] : 0;
    sm[t] = v;
    if (g < NNODES) {
        nout[g] = rsqrtf(fmaxf((float)degout[g], 1.0f));
        nin[g]  = rsqrtf(fmaxf((float)v, 1.0f));
    }
    if (g < 5) tail[g] = sw[g];   // semantic_weight passthrough
    __syncthreads();
#pragma unroll
    for (int off = 1; off < SCAN_B; off <<= 1) {
        int x = (t >= off) ? sm[t - off] : 0;
        __syncthreads();
        sm[t] += x;
        __syncthreads();
    }
    if (g < NNODES) row_off[g] = sm[t] - v;
    if (t == SCAN_B - 1) bsums[blockIdx.x] = sm[t];
}

__global__ void scan_b_k(int* __restrict__ bsums) {
    __shared__ int sm[512];
    int t = threadIdx.x;
    int v = (t < NSBLK) ? bsums[t] : 0;
    sm[t] = v;
    __syncthreads();
#pragma unroll
    for (int off = 1; off < 512; off <<= 1) {
        int x = (t >= off) ? sm[t - off] : 0;
        __syncthreads();
        sm[t] += x;
        __syncthreads();
    }
    if (t < NSBLK) bsums[t] = sm[t] - v;
}

__global__ void scan_c_k(int* __restrict__ row_off, const int* __restrict__ bsums) {
    int g = blockIdx.x * SCAN_B + threadIdx.x;
    if (g < NNODES) row_off[g] += bsums[blockIdx.x];
    if (g == 0) row_off[NNODES] = NEDGES;
}

// ---------------------------------------------------------------- CSR fill
__global__ void fill_csr_k(const int* __restrict__ src, const int* __restrict__ dst,
                           const int* __restrict__ row_off, int* __restrict__ cursor,
                           int* __restrict__ csr_src) {
    int e = blockIdx.x * blockDim.x + threadIdx.x;
    if (e < NEDGES) {
        int d = dst[e];
        int pos = row_off[d] + atomicAdd(cursor + d, 1);
        csr_src[pos] = src[e];
    }
}

// ---------------------------------------------------------------- gather (wave per node, v4)
// avg degree = 3 -> the old serial tail exposed one L2/L3 latency PER EDGE.
// v4: batch up to 8 edge-row loads into independent regs (uniform-branch
// guarded; dead slots contribute exact +0.0f), exposing ONE latency per batch.
template <int EPI>
__global__ __launch_bounds__(256) void gather_k(
    const unsigned short* __restrict__ h, const int* __restrict__ row_off,
    const int* __restrict__ csr_src, const float* __restrict__ nin,
    const float* __restrict__ bias, void* __restrict__ outv)
{
    int node = blockIdx.x * 4 + (threadIdx.x >> 6);
    if (node >= NNODES) return;
    int lane = threadIdx.x & 63;
    int beg = row_off[node], end = row_off[node + 1];
    float a0 = 0.f, a1 = 0.f, a2 = 0.f, a3 = 0.f;
    const size_t loff = (size_t)lane * 4;
    for (int base = beg; base < end; base += 64) {
        int cnt = end - base; if (cnt > 64) cnt = 64;   // wave-uniform
        int idx = csr_src[base + (lane < cnt ? lane : cnt - 1)];   // coalesced
        for (int j = 0; j < cnt; j += 8) {
            uint2 v0 = {0,0}, v1 = {0,0}, v2 = {0,0}, v3 = {0,0};
            uint2 v4 = {0,0}, v5 = {0,0}, v6 = {0,0}, v7 = {0,0};
#define GLD(U, VU)                                                              \
            if (j + U < cnt) {                                                  \
                int s = __shfl(idx, j + U);                                     \
                VU = *(const uint2*)(h + (size_t)s * HID + loff);               \
            }
            GLD(0, v0) GLD(1, v1) GLD(2, v2) GLD(3, v3)
            GLD(4, v4) GLD(5, v5) GLD(6, v6) GLD(7, v7)
#undef GLD
            a0 += (bflo(v0.x) + bflo(v1.x)) + (bflo(v2.x) + bflo(v3.x))
                + (bflo(v4.x) + bflo(v5.x)) + (bflo(v6.x) + bflo(v7.x));
            a1 += (bfhi(v0.x) + bfhi(v1.x)) + (bfhi(v2.x) + bfhi(v3.x))
                + (bfhi(v4.x) + bfhi(v5.x)) + (bfhi(v6.x) + bfhi(v7.x));
            a2 += (bflo(v0.y) + bflo(v1.y)) + (bflo(v2.y) + bflo(v3.y))
                + (bflo(v4.y) + bflo(v5.y)) + (bflo(v6.y) + bflo(v7.y));
            a3 += (bfhi(v0.y) + bfhi(v1.y)) + (bfhi(v2.y) + bfhi(v3.y))
                + (bfhi(v4.y) + bfhi(v5.y)) + (bfhi(v6.y) + bfhi(v7.y));
        }
    }
    if (EPI) {
        float ni = nin[node];
        float4 bb = *(const float4*)(bias + lane * 4);
        float4 o;
        o.x = fmaxf(fmaf(a0, ni, bb.x), 0.f);
        o.y = fmaxf(fmaf(a1, ni, bb.y), 0.f);
        o.z = fmaxf(fmaf(a2, ni, bb.z), 0.f);
        o.w = fmaxf(fmaf(a3, ni, bb.w), 0.f);
        *(float4*)((float*)outv + (size_t)node * HID + lane * 4) = o;
    } else {
        ushort4 o;
        o.x = f2bf(a0); o.y = f2bf(a1); o.z = f2bf(a2); o.w = f2bf(a3);
        *(ushort4*)((unsigned short*)outv + (size_t)node * HID + lane * 4) = o;
    }
}

// ---------------------------------------------------------------- projection MFMA GEMM (v4)
// = v2 structure (best measured: 64m x 256n, 4 waves, 256 thr, BK=32,
//   dbuf LDS for A, B fragments direct from global, 1 barrier/k-step,
//   no vmcnt drain) + v3's n-remap epilogue (fragment slot (j,l15) holds
//   neuron wn*64 + l15*4 + j -> ushort4 stores, 16 instead of 64 stores).
__global__ __launch_bounds__(256, 3) void proj_mfma_k(
    const float* __restrict__ f0, const float* __restrict__ f1, const float* __restrict__ f2,
    const unsigned short* __restrict__ w0, const unsigned short* __restrict__ w1,
    const unsigned short* __restrict__ w2,
    const float* __restrict__ b0, const float* __restrict__ b1, const float* __restrict__ b2,
    const float* __restrict__ nout, unsigned short* __restrict__ h0)
{
    __shared__ unsigned short As[2][64 * 32];   // 2 x 4 KB double buffer

    int bx = blockIdx.x;
    const float* A; const unsigned short* B; const float* bias; const float* rs;
    unsigned short* C; int M, K;
    if (bx < 625)       { A = f0; B = w0; bias = b0; rs = nout;          C = h0;                          M = 40000; K = 512; }
    else if (bx < 1094) { bx -= 625;  A = f1; B = w1; bias = b1; rs = nout + 40000; C = h0 + (size_t)40000 * HID; M = 30000; K = 256; }
    else                { bx -= 1094; A = f2; B = w2; bias = b2; rs = nout + 70000; C = h0 + (size_t)70000 * HID; M = 30000; K = 128; }
    const int m0 = bx * 64;

    const int tid  = threadIdx.x;
    const int wn   = tid >> 6;
    const int lane = tid & 63;
    const int half = lane >> 4;
    const int l15  = lane & 15;

    f32x4 acc[4][4];
#pragma unroll
    for (int i = 0; i < 4; ++i)
#pragma unroll
        for (int j = 0; j < 4; ++j)
#pragma unroll
            for (int r = 0; r < 4; ++r) acc[i][j][r] = 0.f;

    const int arow = tid >> 2, ac = tid & 3;
    const int aslot = ac ^ ((arow >> 1) & 3);
    int agm = m0 + arow; if (agm > M - 1) agm = M - 1;
    const float* ap = A + (size_t)agm * K + ac * 8;

    // n-remap: fragment slot (j,l15) <- weight row wn*64 + l15*4 + j
    const unsigned short* bp = B + (size_t)(wn * 64 + l15 * 4) * K + half * 8;

    const int nT = K >> 5;   // 16 / 8 / 4 k-steps

    // ---- prologue: prefetch step 0 into regs ----
    float4 a0 = *(const float4*)ap;
    float4 a1 = *(const float4*)(ap + 4);
    bf16x8 bcur[4];
#pragma unroll
    for (int j = 0; j < 4; ++j) bcur[j] = *(const bf16x8*)(bp + (size_t)j * K);

    for (int t = 0; t < nT; ++t) {
        const int p = t & 1;
        {   // write staged A (pack fp32->bf16) into LDS buffer p
            uint4 u;
            u.x = pack2(a0.x, a0.y); u.y = pack2(a0.z, a0.w);
            u.z = pack2(a1.x, a1.y); u.w = pack2(a1.z, a1.w);
            *(uint4*)&As[p][(arow * 4 + aslot) * 8] = u;
        }
        asm volatile("s_waitcnt lgkmcnt(0)" ::: "memory");
        __builtin_amdgcn_s_barrier();
        asm volatile("" ::: "memory");
        __builtin_amdgcn_sched_barrier(0);

        // prefetch step t+1 (clamped on last step; harmless hot reload)
        const int tn = (t + 1 < nT) ? t + 1 : t;
        {
            const float* pn = ap + tn * 32;
            a0 = *(const float4*)pn;
            a1 = *(const float4*)(pn + 4);
        }
        bf16x8 bnext[4];
#pragma unroll
        for (int j = 0; j < 4; ++j)
            bnext[j] = *(const bf16x8*)(bp + (size_t)j * K + tn * 32);

        // A fragments from LDS buffer p
        bf16x8 af[4];
#pragma unroll
        for (int i = 0; i < 4; ++i) {
            int m = i * 16 + l15;
            int ca = half ^ ((m >> 1) & 3);
            af[i] = *(const bf16x8*)&As[p][(m * 4 + ca) * 8];
        }
#pragma unroll
        for (int i = 0; i < 4; ++i)
#pragma unroll
            for (int j = 0; j < 4; ++j)
                acc[i][j] = __builtin_amdgcn_mfma_f32_16x16x32_bf16(
                    af[i], bcur[j], acc[i][j], 0, 0, 0);
#pragma unroll
        for (int j = 0; j < 4; ++j) bcur[j] = bnext[j];
    }

    // ---- epilogue: lane's 4 j-values are consecutive cols -> ushort4 stores
    float4 bb = *(const float4*)(bias + wn * 64 + l15 * 4);
#pragma unroll
    for (int i = 0; i < 4; ++i) {
        int mb = m0 + i * 16 + half * 4;
        if (mb >= M) continue;                 // M % 4 == 0: quad all-valid
        float4 rv = *(const float4*)(rs + mb);
#pragma unroll
        for (int r = 0; r < 4; ++r) {
            float rsm = (&rv.x)[r];
            ushort4 o;
            o.x = f2bf((acc[i][0][r] + bb.x) * rsm);
            o.y = f2bf((acc[i][1][r] + bb.y) * rsm);
            o.z = f2bf((acc[i][2][r] + bb.z) * rsm);
            o.w = f2bf((acc[i][3][r] + bb.w) * rsm);
            *(ushort4*)&C[(size_t)(mb + r) * HID + wn * 64 + l15 * 4] = o;
        }
    }
}

// ---------------------------------------------------------------- mid GEMM (v4: v2 structure + remap epilogue)
// h2pre[m][n] = sum_k epi(agg1[m][k]) * W[k][n],
//   epi(x) = relu(x * nin[m] + b1[k]) * nout[m]   (layer-1 epilogue in staging)
__global__ __launch_bounds__(256, 3) void mid_mfma_k(
    const unsigned short* __restrict__ agg1, const unsigned short* __restrict__ wT,
    const float* __restrict__ b1, const float* __restrict__ nin,
    const float* __restrict__ nout, unsigned short* __restrict__ h2)
{
    __shared__ unsigned short As[2][64 * 32];   // 2 x 4 KB double buffer

    const int m0   = blockIdx.x * 64;
    const int tid  = threadIdx.x;
    const int wn   = tid >> 6;
    const int lane = tid & 63;
    const int half = lane >> 4;
    const int l15  = lane & 15;

    f32x4 acc[4][4];
#pragma unroll
    for (int i = 0; i < 4; ++i)
#pragma unroll
        for (int j = 0; j < 4; ++j)
#pragma unroll
            for (int r = 0; r < 4; ++r) acc[i][j][r] = 0.f;

    const int arow = tid >> 2, ac = tid & 3;
    const int aslot = ac ^ ((arow >> 1) & 3);
    int agm = m0 + arow; if (agm > NNODES - 1) agm = NNODES - 1;
    const float ni = nin[agm], no = nout[agm];
    const unsigned short* ap = agg1 + (size_t)agm * HID + ac * 8;
    const unsigned short* bp = wT + (size_t)(wn * 64 + l15 * 4) * 256 + half * 8;

    // ---- prologue ----
    uint4 au = *(const uint4*)ap;
    bf16x8 bcur[4];
#pragma unroll
    for (int j = 0; j < 4; ++j) bcur[j] = *(const bf16x8*)(bp + j * 256);

#pragma unroll 2
    for (int t = 0; t < 8; ++t) {
        const int p = t & 1;
        {   // A stage: bf16 agg1 chunk -> layer-1 epilogue -> bf16 -> LDS
            const int k0 = t * 32;
            float4 c0 = *(const float4*)(b1 + k0 + ac * 8);
            float4 c1 = *(const float4*)(b1 + k0 + ac * 8 + 4);
            float x0 = fmaxf(fmaf(bflo(au.x), ni, c0.x), 0.f) * no;
            float x1 = fmaxf(fmaf(bfhi(au.x), ni, c0.y), 0.f) * no;
            float x2 = fmaxf(fmaf(bflo(au.y), ni, c0.z), 0.f) * no;
            float x3 = fmaxf(fmaf(bfhi(au.y), ni, c0.w), 0.f) * no;
            float x4 = fmaxf(fmaf(bflo(au.z), ni, c1.x), 0.f) * no;
            float x5 = fmaxf(fmaf(bfhi(au.z), ni, c1.y), 0.f) * no;
            float x6 = fmaxf(fmaf(bflo(au.w), ni, c1.z), 0.f) * no;
            float x7 = fmaxf(fmaf(bfhi(au.w), ni, c1.w), 0.f) * no;
            uint4 o;
            o.x = pack2(x0, x1); o.y = pack2(x2, x3);
            o.z = pack2(x4, x5); o.w = pack2(x6, x7);
            *(uint4*)&As[p][(arow * 4 + aslot) * 8] = o;
        }
        asm volatile("s_waitcnt lgkmcnt(0)" ::: "memory");
        __builtin_amdgcn_s_barrier();
        asm volatile("" ::: "memory");
        __builtin_amdgcn_sched_barrier(0);

        const int tn = (t + 1 < 8) ? t + 1 : t;
        au = *(const uint4*)(ap + tn * 32);
        bf16x8 bnext[4];
#pragma unroll
        for (int j = 0; j < 4; ++j)
            bnext[j] = *(const bf16x8*)(bp + j * 256 + tn * 32);

        bf16x8 af[4];
#pragma unroll
        for (int i = 0; i < 4; ++i) {
            int m = i * 16 + l15;
            int ca = half ^ ((m >> 1) & 3);
            af[i] = *(const bf16x8*)&As[p][(m * 4 + ca) * 8];
        }
#pragma unroll
        for (int i = 0; i < 4; ++i)
#pragma unroll
            for (int j = 0; j < 4; ++j)
                acc[i][j] = __builtin_amdgcn_mfma_f32_16x16x32_bf16(
                    af[i], bcur[j], acc[i][j], 0, 0, 0);
#pragma unroll
        for (int j = 0; j < 4; ++j) bcur[j] = bnext[j];
    }

#pragma unroll
    for (int i = 0; i < 4; ++i) {
        int mb = m0 + i * 16 + half * 4;
        if (mb >= NNODES) continue;            // NNODES % 4 == 0
#pragma unroll
        for (int r = 0; r < 4; ++r) {
            ushort4 o;
            o.x = f2bf(acc[i][0][r]);
            o.y = f2bf(acc[i][1][r]);
            o.z = f2bf(acc[i][2][r]);
            o.w = f2bf(acc[i][3][r]);
            *(ushort4*)&h2[(size_t)(mb + r) * HID + wn * 64 + l15 * 4] = o;
        }
    }
}

// ---------------------------------------------------------------- launch
extern "C" void kernel_launch(void* const* d_in, const int* in_sizes, int n_in,
                              void* d_out, int out_size, void* d_ws, size_t ws_size,
                              hipStream_t stream)
{
    const float* feat0    = (const float*)d_in[0];
    const float* feat1    = (const float*)d_in[1];
    const float* feat2    = (const float*)d_in[2];
    const float* fc_w0    = (const float*)d_in[3];
    const float* fc_b0    = (const float*)d_in[4];
    const float* fc_w1    = (const float*)d_in[5];
    const float* fc_b1    = (const float*)d_in[6];
    const float* fc_w2    = (const float*)d_in[7];
    const float* fc_b2    = (const float*)d_in[8];
    const float* gc1_bias = (const float*)d_in[9];
    const float* gc2_w    = (const float*)d_in[10];
    const float* gc2_bias = (const float*)d_in[11];
    const float* sw       = (const float*)d_in[12];
    const int*   src      = (const int*)d_in[13];
    const int*   dst      = (const int*)d_in[14];

    // ---- workspace layout ----
    unsigned short* h0b  = (unsigned short*)d_ws;          // NH bf16 (later h2pre)
    unsigned short* agg1 = h0b + NH;                       // NH bf16
    unsigned short* h2b  = h0b;    // alias: h0 dead after gather1
    unsigned short* w0b  = agg1 + NH;                      // 256*512
    unsigned short* w1b  = w0b + 131072;                   // 256*256
    unsigned short* w2b  = w1b + 65536;                    // 256*128
    unsigned short* w2Tb = w2b + 32768;                    // 256*256 (n-major)
    float* nout = (float*)(w2Tb + 65536);
    float* nin  = nout + NNODES;
    int* deg_out = (int*)(nin + NNODES);
    int* deg_in  = deg_out + NNODES;
    int* cursor  = deg_in + NNODES;
    int* row_off = cursor + NNODES;       // NNODES+1
    int* bsums   = row_off + NNODES + 1;  // 512
    int* csr_src = bsums + 512;           // NEDGES
    float* out   = (float*)d_out;

    // ---- graph preprocessing + weight conversion ----
    zero_i32_k<<<(3 * NNODES + 255) / 256, 256, 0, stream>>>(deg_out, 3 * NNODES);
    cvt_weights_k<<<480, 256, 0, stream>>>(fc_w0, fc_w1, fc_w2, gc2_w,
                                           w0b, w1b, w2b, w2Tb);
    count_deg_k<<<(NEDGES + 255) / 256, 256, 0, stream>>>(src, dst, deg_out, deg_in);
    scan_a_k<<<NSBLK, SCAN_B, 0, stream>>>(deg_in, deg_out, row_off, bsums,
                                           nout, nin, sw, out + NH);
    scan_b_k<<<1, 512, 0, stream>>>(bsums);
    scan_c_k<<<NSBLK, SCAN_B, 0, stream>>>(row_off, bsums);
    fill_csr_k<<<(NEDGES + 255) / 256, 256, 0, stream>>>(src, dst, row_off, cursor, csr_src);

    // ---- projections: h0 = (feat @ W.T + b)*nout  [bf16] ----
    proj_mfma_k<<<1563, 256, 0, stream>>>(feat0, feat1, feat2, w0b, w1b, w2b,
                                          fc_b0, fc_b1, fc_b2, nout, h0b);

    // ---- layer 1 aggregate (raw sum): agg1 = A h0 ----
    gather_k<0><<<(NNODES + 3) / 4, 256, 0, stream>>>(h0b, row_off, csr_src,
                                                      nullptr, nullptr, agg1);

    // ---- h2pre = relu(agg1*nin + b1)*nout @ W   (epilogue fused into A-staging) ----
    mid_mfma_k<<<1563, 256, 0, stream>>>(agg1, w2Tb, gc1_bias, nin, nout, h2b);

    // ---- layer 2 aggregate + final epilogue -> d_out (fp32) ----
    gather_k<1><<<(NNODES + 3) / 4, 256, 0, stream>>>(h2b, row_off, csr_src,
                                                      nin, gc2_bias, out);
}